// Round 24
// baseline (59.330 us; speedup 1.0000x reference)
//
#include <hip/hip_runtime.h>

// Problem constants (fixed by the reference)
#define BATCH 128
#define C 64
#define L 4096
#define K 31

#define NT 512               // 8 waves; one block covers all of L
#define NWAVE 8
#define CG 4                 // channel groups (blocks split over channels)
#define CPB (C / CG)         // 16 channels per block
#define RW 8                 // samples/outputs per lane
#define WTILE 512            // outputs per wave (64 lanes * RW); 8 waves = L

typedef float floatx4 __attribute__((ext_vector_type(4)));
typedef float floatx2 __attribute__((ext_vector_type(2)));
typedef unsigned short ushortx8 __attribute__((ext_vector_type(8)));
typedef unsigned short ushortx4 __attribute__((ext_vector_type(4)));

__device__ __forceinline__ floatx4 ld4(const float* p) {
    return *reinterpret_cast<const floatx4*>(p);
}

__device__ __forceinline__ unsigned short f2bf(float f) {   // RNE
    unsigned int u = __float_as_uint(f);
    return (unsigned short)((u + 0x7FFFu + ((u >> 16) & 1u)) >> 16);
}
__device__ __forceinline__ float bf2f(unsigned short h) {
    return __uint_as_float(((unsigned int)h) << 16);
}

// SALU splat: both 32-bit halves of a 64-bit scalar = bits of f.
// Runs on the scalar pipe, parallel to VALU — free wrt the VALU bottleneck.
__device__ __forceinline__ unsigned long long wsplat(float f) {
    const unsigned long long u = (unsigned long long)__float_as_uint(f);
    return (u << 32) | u;
}

// ---- K1: SpH[cg][b][l] (bf16) = sum_{i in cg} sum_k w[i,k]*x[b,i,l+15-k]
// Packed-fp32 scatter with TRUE v_pk_fma_f32: P2[j]=(P[2j],P[2j+1]).
// All VOP3P operands are 64-bit pairs: d,a in VGPR pairs, weight in an
// even-aligned SGPR pair with both halves equal (r23's lone-SGPR operand
// was the assembler rejection). Default op_sel (no modifiers) is correct
// since the weight pair is a splat.
#define PK(d, a, ws)                                                       \
    asm("v_pk_fma_f32 %0, %1, %2, %0" : "+v"(d) : "v"(a), "s"(ws));

#define PEV(k) { const unsigned long long ws = wsplat(wp[k]);              \
    PK(P2[(k)/2+0], e0, ws) PK(P2[(k)/2+1], e1, ws)                        \
    PK(P2[(k)/2+2], e2, ws) PK(P2[(k)/2+3], e3, ws) }
#define POD(k) { const unsigned long long ws = wsplat(wp[k]);              \
    PK(P2[((k)-1)/2+0], g0, ws) PK(P2[((k)-1)/2+1], g1, ws)                \
    PK(P2[((k)-1)/2+2], g2, ws) PK(P2[((k)-1)/2+3], g3, ws)                \
    PK(P2[((k)-1)/2+4], g4, ws) }

__global__ __launch_bounds__(NT, 2)
void computeS_kernel(const float* __restrict__ x,
                     const float* __restrict__ w,
                     unsigned short* __restrict__ SpH) {
    __shared__ float exL1[NWAVE][8];   // lane63's P[23..30]
    __shared__ float exL2a[NWAVE][8];  // lane62's P[31..37]
    __shared__ float exL2b[NWAVE][8];  // lane63's P[31..37]
    __shared__ float exR1[NWAVE][8];   // lane0's  P[7..14]
    __shared__ float exR2a[NWAVE][8];  // lane1's  P[0..6]
    __shared__ float exR2b[NWAVE][8];  // lane0's  P[0..6]

    const int tid  = threadIdx.x;
    const int wv   = tid >> 6;
    const int lane = tid & 63;
    const int b    = blockIdx.x;          // 0..127
    const int cg   = blockIdx.y;          // 0..3
    const int l0   = wv * WTILE + lane * RW;
    const int i0   = cg * CPB;
    const float* xb = x + (long)b * C * L;

    floatx2 P2[19];
#pragma unroll
    for (int j = 0; j < 19; ++j) P2[j] = 0.f;

    const float* xi = xb + (long)i0 * L + l0;
    floatx4 o0 = ld4(xi), o1 = ld4(xi + 4);

    for (int c = 0; c < CPB; ++c) {
        // 1-deep prefetch of next channel's own samples
        floatx4 n0 = o0, n1 = o1;
        if (c + 1 < CPB) { n0 = ld4(xi + L); n1 = ld4(xi + L + 4); }

        // aligned pairs (halves of o0/o1) and shifted pairs (~8 movs)
        floatx2 e0, e1, e2, e3, g0, g1, g2, g3, g4;
        e0.x = o0.x; e0.y = o0.y;  e1.x = o0.z; e1.y = o0.w;
        e2.x = o1.x; e2.y = o1.y;  e3.x = o1.z; e3.y = o1.w;
        g0.x = 0.f;  g0.y = o0.x;  g1.x = o0.y; g1.y = o0.z;
        g2.x = o0.w; g2.y = o1.x;  g3.x = o1.y; g3.y = o1.z;
        g4.x = o1.w; g4.y = 0.f;

        const float* wp = w + (i0 + c) * K;   // block-uniform -> s_load
        PEV(0)  POD(1)  PEV(2)  POD(3)  PEV(4)  POD(5)  PEV(6)  POD(7)
        PEV(8)  POD(9)  PEV(10) POD(11) PEV(12) POD(13) PEV(14) POD(15)
        PEV(16) POD(17) PEV(18) POD(19) PEV(20) POD(21) PEV(22) POD(23)
        PEV(24) POD(25) PEV(26) POD(27) PEV(28) POD(29) PEV(30)

        o0 = n0; o1 = n1;
        xi += L;
    }

    // unpack to the proven end-phase layout
    float P[38];
#pragma unroll
    for (int j = 0; j < 19; ++j) { P[2 * j] = P2[j].x; P[2 * j + 1] = P2[j].y; }

    // ---- wave-edge partials to LDS (once per kernel; r13-proven) ----
    if (lane == 63) {
#pragma unroll
        for (int j = 0; j < 8; ++j) exL1[wv][j] = P[23 + j];
#pragma unroll
        for (int j = 0; j < 7; ++j) exL2b[wv][j] = P[31 + j];
    }
    if (lane == 62) {
#pragma unroll
        for (int j = 0; j < 7; ++j) exL2a[wv][j] = P[31 + j];
    }
    if (lane == 0) {
#pragma unroll
        for (int j = 0; j < 8; ++j) exR1[wv][j] = P[7 + j];
#pragma unroll
        for (int j = 0; j < 7; ++j) exR2b[wv][j] = P[j];
    }
    if (lane == 1) {
#pragma unroll
        for (int j = 0; j < 7; ++j) exR2a[wv][j] = P[j];
    }
    __syncthreads();

    float res[RW];
#pragma unroll
    for (int r = 0; r < RW; ++r) res[r] = P[15 + r];

    // up1: lane-1's P[23+r]   (wave edge via LDS; grid edge -> 0)
#pragma unroll
    for (int r = 0; r < 8; ++r) {
        float v = __shfl_up(P[23 + r], 1, 64);
        if (lane == 0) v = (wv > 0) ? exL1[wv - 1][r] : 0.f;
        res[r] += v;
    }
    // up2: lane-2's P[31+r], r=0..6
#pragma unroll
    for (int r = 0; r < 7; ++r) {
        float v = __shfl_up(P[31 + r], 2, 64);
        if (lane == 0)      v = (wv > 0) ? exL2a[wv - 1][r] : 0.f;
        else if (lane == 1) v = (wv > 0) ? exL2b[wv - 1][r] : 0.f;
        res[r] += v;
    }
    // down1: lane+1's P[7+r]
#pragma unroll
    for (int r = 0; r < 8; ++r) {
        float v = __shfl_down(P[7 + r], 1, 64);
        if (lane == 63) v = (wv < NWAVE - 1) ? exR1[wv + 1][r] : 0.f;
        res[r] += v;
    }
    // down2: lane+2's P[r-1], r=1..7
#pragma unroll
    for (int r = 1; r < 8; ++r) {
        float v = __shfl_down(P[r - 1], 2, 64);
        if (lane == 63)      v = (wv < NWAVE - 1) ? exR2a[wv + 1][r - 1] : 0.f;
        else if (lane == 62) v = (wv < NWAVE - 1) ? exR2b[wv + 1][r - 1] : 0.f;
        res[r] += v;
    }

    // pack to bf16 (RNE) and store 16 B
    ushortx8 hv;
#pragma unroll
    for (int r = 0; r < RW; ++r) hv[r] = f2bf(res[r]);
    *reinterpret_cast<ushortx8*>(SpH + ((long)cg * BATCH + b) * L + l0) = hv;
}

// ---- K2: out[b,o,l] = sum_cg bf2f(SpH[cg][b][l]) — dense streaming broadcast.
__global__ __launch_bounds__(256)
void broadcast_kernel(const unsigned short* __restrict__ SpH,
                      float* __restrict__ out) {
    const int lane = threadIdx.x & 63;
    const int og   = threadIdx.x >> 6;            // 0..3
    const int b    = blockIdx.y;
    const int l4   = blockIdx.x * 64 + lane;      // float4 column index
    const long sbase = (long)b * L + (long)l4 * 4;

    floatx4 v = 0.f;
#pragma unroll
    for (int cg = 0; cg < CG; ++cg) {
        const ushortx4 h = *reinterpret_cast<const ushortx4*>(SpH + (long)cg * BATCH * L + sbase);
        v.x += bf2f(h.x); v.y += bf2f(h.y); v.z += bf2f(h.z); v.w += bf2f(h.w);
    }

    float* ob = out + ((long)b * C + og * 16) * L + (long)l4 * 4;
#pragma unroll
    for (int o = 0; o < 16; ++o)
        __builtin_nontemporal_store(v, reinterpret_cast<floatx4*>(ob + (long)o * L));
}

// ---- Fallback (proven round-3 fused kernel) if ws too small ----
#define FB_R 4
#define FB_TILE (256 * FB_R)
#define FB_WIN 36
__global__ __launch_bounds__(256)
void fused_kernel(const float* __restrict__ x,
                  const float* __restrict__ w,
                  float* __restrict__ out) {
    const int tid = threadIdx.x;
    const int tile = blockIdx.x;
    const int b = blockIdx.y;
    const int l0 = tile * FB_TILE + tid * FB_R;
    float acc[FB_R] = {0.f, 0.f, 0.f, 0.f};
    const float* xb = x + (long)b * C * L;
    const bool interior = (l0 >= 16) && (l0 + 20 <= L);
    if (interior) {
        const float* xw = xb + (l0 - 16);
#pragma unroll 2
        for (int i = 0; i < C; ++i) {
            float win[FB_WIN];
            const floatx4* p = reinterpret_cast<const floatx4*>(xw + (long)i * L);
#pragma unroll
            for (int j = 0; j < FB_WIN / 4; ++j)
                reinterpret_cast<floatx4*>(win)[j] = p[j];
            const float* wp = w + i * K;
#pragma unroll
            for (int k = 0; k < K; ++k) {
                const float wk = wp[k];
#pragma unroll
                for (int r = 0; r < FB_R; ++r)
                    acc[r] += wk * win[r + 31 - k];
            }
        }
    } else {
        for (int i = 0; i < C; ++i) {
            const float* xi = xb + (long)i * L;
            float win[FB_WIN];
#pragma unroll
            for (int j = 0; j < FB_WIN; ++j) {
                const int g = l0 - 16 + j;
                win[j] = (g >= 0 && g < L) ? xi[g] : 0.f;
            }
            const float* wp = w + i * K;
#pragma unroll
            for (int k = 0; k < K; ++k) {
                const float wk = wp[k];
#pragma unroll
                for (int r = 0; r < FB_R; ++r)
                    acc[r] += wk * win[r + 31 - k];
            }
        }
    }
    float* op = out + (long)b * C * L + l0;
    floatx4 v; v.x = acc[0]; v.y = acc[1]; v.z = acc[2]; v.w = acc[3];
#pragma unroll
    for (int o = 0; o < C; ++o)
        __builtin_nontemporal_store(v, reinterpret_cast<floatx4*>(op + (long)o * L));
}

extern "C" void kernel_launch(void* const* d_in, const int* in_sizes, int n_in,
                              void* d_out, int out_size, void* d_ws, size_t ws_size,
                              hipStream_t stream) {
    const float* x = (const float*)d_in[0];   // [B, C, L] fp32
    const float* w = (const float*)d_in[1];   // [C, C, K] fp32; o=0 slice used
    float* out = (float*)d_out;               // [B, C, L] fp32

    const size_t sp_bytes = (size_t)CG * BATCH * L * sizeof(unsigned short);   // 4 MB
    if (ws_size >= sp_bytes) {
        unsigned short* SpH = (unsigned short*)d_ws;
        dim3 grid1(BATCH, CG);                    // 128 x 4 = 512 blocks x 8 waves
        computeS_kernel<<<grid1, NT, 0, stream>>>(x, w, SpH);
        dim3 grid2(L / 256, BATCH);               // 2048 blocks
        broadcast_kernel<<<grid2, 256, 0, stream>>>(SpH, out);
    } else {
        dim3 grid(L / FB_TILE, BATCH);
        fused_kernel<<<grid, 256, 0, stream>>>(x, w, out);
    }
}

// Round 25
// 57.823 us; speedup vs baseline: 1.0261x; 1.0261x over previous
//
#include <hip/hip_runtime.h>

// Problem constants (fixed by the reference)
#define BATCH 128
#define C 64
#define L 4096
#define K 31

#define NT 512               // 8 waves; one block covers all of L
#define NWAVE 8
#define CG 4                 // channel groups (blocks split over channels)
#define CPB (C / CG)         // 16 channels per block
#define RW 8                 // samples/outputs per lane
#define WTILE 512            // outputs per wave (64 lanes * RW); 8 waves = L

typedef float floatx4 __attribute__((ext_vector_type(4)));
typedef unsigned short ushortx8 __attribute__((ext_vector_type(8)));
typedef unsigned short ushortx4 __attribute__((ext_vector_type(4)));

__device__ __forceinline__ floatx4 ld4(const float* p) {
    return *reinterpret_cast<const floatx4*>(p);
}

__device__ __forceinline__ unsigned short f2bf(float f) {   // RNE
    unsigned int u = __float_as_uint(f);
    return (unsigned short)((u + 0x7FFFu + ((u >> 16) & 1u)) >> 16);
}
__device__ __forceinline__ float bf2f(unsigned short h) {
    return __uint_as_float(((unsigned int)h) << 16);
}

// ---- K1: SpH[cg][b][l] (bf16) = sum_{i in cg} sum_k w[i,k] * x[b,i,l+15-k]
// r19's proven scatter loop (CG=4, 1-deep prefetch, 2-hop end exchange);
// partials stored as bf16 to halve the scratch round-trip (8->4 MB each way).
#define KSTEP(k) { const float wk = wp[k];                              \
    P[(k)+0] += wk * o0.x; P[(k)+1] += wk * o0.y;                       \
    P[(k)+2] += wk * o0.z; P[(k)+3] += wk * o0.w;                       \
    P[(k)+4] += wk * o1.x; P[(k)+5] += wk * o1.y;                       \
    P[(k)+6] += wk * o1.z; P[(k)+7] += wk * o1.w; }

__global__ __launch_bounds__(NT, 2)
void computeS_kernel(const float* __restrict__ x,
                     const float* __restrict__ w,
                     unsigned short* __restrict__ SpH) {
    __shared__ float exL1[NWAVE][8];   // lane63's P[23..30]
    __shared__ float exL2a[NWAVE][8];  // lane62's P[31..37]
    __shared__ float exL2b[NWAVE][8];  // lane63's P[31..37]
    __shared__ float exR1[NWAVE][8];   // lane0's  P[7..14]
    __shared__ float exR2a[NWAVE][8];  // lane1's  P[0..6]
    __shared__ float exR2b[NWAVE][8];  // lane0's  P[0..6]

    const int tid  = threadIdx.x;
    const int wv   = tid >> 6;
    const int lane = tid & 63;
    const int b    = blockIdx.x;          // 0..127
    const int cg   = blockIdx.y;          // 0..3
    const int l0   = wv * WTILE + lane * RW;
    const int i0   = cg * CPB;
    const float* xb = x + (long)b * C * L;

    float P[38] = {};   // P[j] <-> output l0 - 15 + j

    const float* xi = xb + (long)i0 * L + l0;
    floatx4 o0 = ld4(xi), o1 = ld4(xi + 4);

    for (int c = 0; c < CPB; ++c) {
        // 1-deep prefetch of next channel's own samples
        floatx4 n0 = o0, n1 = o1;
        if (c + 1 < CPB) { n0 = ld4(xi + L); n1 = ld4(xi + L + 4); }

        const float* wp = w + (i0 + c) * K;   // block-uniform -> s_load
        KSTEP(0)  KSTEP(1)  KSTEP(2)  KSTEP(3)  KSTEP(4)  KSTEP(5)
        KSTEP(6)  KSTEP(7)  KSTEP(8)  KSTEP(9)  KSTEP(10) KSTEP(11)
        KSTEP(12) KSTEP(13) KSTEP(14) KSTEP(15) KSTEP(16) KSTEP(17)
        KSTEP(18) KSTEP(19) KSTEP(20) KSTEP(21) KSTEP(22) KSTEP(23)
        KSTEP(24) KSTEP(25) KSTEP(26) KSTEP(27) KSTEP(28) KSTEP(29)
        KSTEP(30)

        o0 = n0; o1 = n1;
        xi += L;
    }

    // ---- wave-edge partials to LDS (once per kernel; r13-proven) ----
    if (lane == 63) {
#pragma unroll
        for (int j = 0; j < 8; ++j) exL1[wv][j] = P[23 + j];
#pragma unroll
        for (int j = 0; j < 7; ++j) exL2b[wv][j] = P[31 + j];
    }
    if (lane == 62) {
#pragma unroll
        for (int j = 0; j < 7; ++j) exL2a[wv][j] = P[31 + j];
    }
    if (lane == 0) {
#pragma unroll
        for (int j = 0; j < 8; ++j) exR1[wv][j] = P[7 + j];
#pragma unroll
        for (int j = 0; j < 7; ++j) exR2b[wv][j] = P[j];
    }
    if (lane == 1) {
#pragma unroll
        for (int j = 0; j < 7; ++j) exR2a[wv][j] = P[j];
    }
    __syncthreads();

    float res[RW];
#pragma unroll
    for (int r = 0; r < RW; ++r) res[r] = P[15 + r];

    // up1: lane-1's P[23+r]   (wave edge via LDS; grid edge -> 0)
#pragma unroll
    for (int r = 0; r < 8; ++r) {
        float v = __shfl_up(P[23 + r], 1, 64);
        if (lane == 0) v = (wv > 0) ? exL1[wv - 1][r] : 0.f;
        res[r] += v;
    }
    // up2: lane-2's P[31+r], r=0..6
#pragma unroll
    for (int r = 0; r < 7; ++r) {
        float v = __shfl_up(P[31 + r], 2, 64);
        if (lane == 0)      v = (wv > 0) ? exL2a[wv - 1][r] : 0.f;
        else if (lane == 1) v = (wv > 0) ? exL2b[wv - 1][r] : 0.f;
        res[r] += v;
    }
    // down1: lane+1's P[7+r]
#pragma unroll
    for (int r = 0; r < 8; ++r) {
        float v = __shfl_down(P[7 + r], 1, 64);
        if (lane == 63) v = (wv < NWAVE - 1) ? exR1[wv + 1][r] : 0.f;
        res[r] += v;
    }
    // down2: lane+2's P[r-1], r=1..7
#pragma unroll
    for (int r = 1; r < 8; ++r) {
        float v = __shfl_down(P[r - 1], 2, 64);
        if (lane == 63)      v = (wv < NWAVE - 1) ? exR2a[wv + 1][r - 1] : 0.f;
        else if (lane == 62) v = (wv < NWAVE - 1) ? exR2b[wv + 1][r - 1] : 0.f;
        res[r] += v;
    }

    // pack to bf16 (RNE) and store 16 B
    ushortx8 hv;
#pragma unroll
    for (int r = 0; r < RW; ++r) hv[r] = f2bf(res[r]);
    *reinterpret_cast<ushortx8*>(SpH + ((long)cg * BATCH + b) * L + l0) = hv;
}

// ---- K2: out[b,o,l] = sum_cg bf2f(SpH[cg][b][l]) — dense streaming broadcast.
__global__ __launch_bounds__(256)
void broadcast_kernel(const unsigned short* __restrict__ SpH,
                      float* __restrict__ out) {
    const int lane = threadIdx.x & 63;
    const int og   = threadIdx.x >> 6;            // 0..3
    const int b    = blockIdx.y;
    const int l4   = blockIdx.x * 64 + lane;      // float4 column index
    const long sbase = (long)b * L + (long)l4 * 4;

    floatx4 v = 0.f;
#pragma unroll
    for (int cg = 0; cg < CG; ++cg) {
        const ushortx4 h = *reinterpret_cast<const ushortx4*>(SpH + (long)cg * BATCH * L + sbase);
        v.x += bf2f(h.x); v.y += bf2f(h.y); v.z += bf2f(h.z); v.w += bf2f(h.w);
    }

    float* ob = out + ((long)b * C + og * 16) * L + (long)l4 * 4;
#pragma unroll
    for (int o = 0; o < 16; ++o)
        __builtin_nontemporal_store(v, reinterpret_cast<floatx4*>(ob + (long)o * L));
}

// ---- Fallback (proven round-3 fused kernel) if ws too small ----
#define FB_R 4
#define FB_TILE (256 * FB_R)
#define FB_WIN 36
__global__ __launch_bounds__(256)
void fused_kernel(const float* __restrict__ x,
                  const float* __restrict__ w,
                  float* __restrict__ out) {
    const int tid = threadIdx.x;
    const int tile = blockIdx.x;
    const int b = blockIdx.y;
    const int l0 = tile * FB_TILE + tid * FB_R;
    float acc[FB_R] = {0.f, 0.f, 0.f, 0.f};
    const float* xb = x + (long)b * C * L;
    const bool interior = (l0 >= 16) && (l0 + 20 <= L);
    if (interior) {
        const float* xw = xb + (l0 - 16);
#pragma unroll 2
        for (int i = 0; i < C; ++i) {
            float win[FB_WIN];
            const floatx4* p = reinterpret_cast<const floatx4*>(xw + (long)i * L);
#pragma unroll
            for (int j = 0; j < FB_WIN / 4; ++j)
                reinterpret_cast<floatx4*>(win)[j] = p[j];
            const float* wp = w + i * K;
#pragma unroll
            for (int k = 0; k < K; ++k) {
                const float wk = wp[k];
#pragma unroll
                for (int r = 0; r < FB_R; ++r)
                    acc[r] += wk * win[r + 31 - k];
            }
        }
    } else {
        for (int i = 0; i < C; ++i) {
            const float* xi = xb + (long)i * L;
            float win[FB_WIN];
#pragma unroll
            for (int j = 0; j < FB_WIN; ++j) {
                const int g = l0 - 16 + j;
                win[j] = (g >= 0 && g < L) ? xi[g] : 0.f;
            }
            const float* wp = w + i * K;
#pragma unroll
            for (int k = 0; k < K; ++k) {
                const float wk = wp[k];
#pragma unroll
                for (int r = 0; r < FB_R; ++r)
                    acc[r] += wk * win[r + 31 - k];
            }
        }
    }
    float* op = out + (long)b * C * L + l0;
    floatx4 v; v.x = acc[0]; v.y = acc[1]; v.z = acc[2]; v.w = acc[3];
#pragma unroll
    for (int o = 0; o < C; ++o)
        __builtin_nontemporal_store(v, reinterpret_cast<floatx4*>(op + (long)o * L));
}

extern "C" void kernel_launch(void* const* d_in, const int* in_sizes, int n_in,
                              void* d_out, int out_size, void* d_ws, size_t ws_size,
                              hipStream_t stream) {
    const float* x = (const float*)d_in[0];   // [B, C, L] fp32
    const float* w = (const float*)d_in[1];   // [C, C, K] fp32; o=0 slice used
    float* out = (float*)d_out;               // [B, C, L] fp32

    const size_t sp_bytes = (size_t)CG * BATCH * L * sizeof(unsigned short);   // 4 MB
    if (ws_size >= sp_bytes) {
        unsigned short* SpH = (unsigned short*)d_ws;
        dim3 grid1(BATCH, CG);                    // 128 x 4 = 512 blocks x 8 waves
        computeS_kernel<<<grid1, NT, 0, stream>>>(x, w, SpH);
        dim3 grid2(L / 256, BATCH);               // 2048 blocks
        broadcast_kernel<<<grid2, 256, 0, stream>>>(SpH, out);
    } else {
        dim3 grid(L / FB_TILE, BATCH);
        fused_kernel<<<grid, 256, 0, stream>>>(x, w, out);
    }
}